// Round 4
// baseline (420.712 us; speedup 1.0000x reference)
//
#include <hip/hip_runtime.h>
#include <stdint.h>
#include <math.h>

#define N_ROWS 2048
#define M_CAND 131072
#define DIMK 128
#define DOUT 10
#define COLS_PER_BLOCK 1024       // one chunk per block; M = 128 * 1024 exactly
#define SUB_ITERS 16              // 16 sub-tiles of 64 candidates
#define CHUNKS (M_CAND / COLS_PER_BLOCK)   // 128
#define LOG2E 1.4426950408889634f
#define L2E2 (LOG2E * LOG2E)      // pre-scale so exp2(-sqrt(sq')) == exp(-sqrt(sq))

typedef __attribute__((ext_vector_type(8))) __bf16 bf16x8;   // MFMA A/B frag (4 VGPRs)
typedef __attribute__((ext_vector_type(8))) short s16x8;     // raw bf16 storage vec
typedef __attribute__((ext_vector_type(4))) float f32x4;     // MFMA C/D frag
typedef __attribute__((ext_vector_type(2))) float f32x2;     // v_pk_* pair
typedef __attribute__((address_space(3))) void lds_void;
typedef const __attribute__((address_space(1))) void gbl_void;

__device__ __forceinline__ short f2bf(float f) {   // RNE fp32->bf16
  union { float f; unsigned u; } v; v.f = f;
  return (short)((v.u + 0x7fffu + ((v.u >> 16) & 1u)) >> 16);
}
__device__ __forceinline__ float bf2f(short h) {
  union { unsigned u; float f; } v;
  v.u = ((unsigned)(unsigned short)h) << 16; return v.f;
}
__device__ __forceinline__ float fast_sqrtf(float x) {
#if __has_builtin(__builtin_amdgcn_sqrtf)
  return __builtin_amdgcn_sqrtf(x);
#else
  return sqrtf(x);
#endif
}
__device__ __forceinline__ float fast_exp2f(float x) {
#if __has_builtin(__builtin_amdgcn_exp2f)
  return __builtin_amdgcn_exp2f(x);
#else
  return exp2f(x);
#endif
}

// Swizzled 64x128 bf16 tile: LDS slot (r,s) [16B granules] holds global granule g = s^(r&15).
__device__ __forceinline__ void stage64(const short* gbase, short* lds, int t) {
  int w = t >> 6;
#pragma unroll
  for (int i = 0; i < 4; ++i) {
    int flat = i * 256 + t;
    int r = flat >> 4, s = flat & 15;
    int g = s ^ (r & 15);
    const short* src = gbase + r * DIMK + g * 8;
    short* dst = lds + (i * 256 + w * 64) * 8;   // wave-uniform base; HW adds lane*16B
    __builtin_amdgcn_global_load_lds((gbl_void*)src, (lds_void*)dst, 16, 0, 0);
  }
}

// 64x64 wave tile, K=128 (encoder; both operands in swizzled 128x128 LDS tiles)
__device__ __forceinline__ void mfma_tile(const short* As, const short* Bs,
                                          f32x4 acc[4][4], int wrow, int wcol,
                                          int quad, int l15) {
#pragma unroll
  for (int ks = 0; ks < 4; ++ks) {
    int slot = (ks * 4 + quad) ^ l15;
    bf16x8 a[4], b[4];
#pragma unroll
    for (int i = 0; i < 4; ++i) {
      a[i] = *(const bf16x8*)(As + (wrow + i * 16 + l15) * DIMK + slot * 8);
      b[i] = *(const bf16x8*)(Bs + (wcol + i * 16 + l15) * DIMK + slot * 8);
    }
#pragma unroll
    for (int i = 0; i < 4; ++i)
#pragma unroll
      for (int j = 0; j < 4; ++j)
        acc[i][j] = __builtin_amdgcn_mfma_f32_16x16x32_bf16(a[i], b[j], acc[i][j], 0, 0, 0);
  }
}

// ---------------- preprocessing: class-sort candidates (exact, no padding) ------------
// hist also zeroes the accum[2048][16] output accumulator (first 128 blocks).
__global__ __launch_bounds__(256) void hist_kernel(const int* __restrict__ y,
                                                   int* __restrict__ cnt,
                                                   float* __restrict__ accum) {
  __shared__ int h[DOUT];
  int t = threadIdx.x;
  if (blockIdx.x < 128) accum[blockIdx.x * 256 + t] = 0.f;   // 2048*16 floats
  if (t < DOUT) h[t] = 0;
  __syncthreads();
  atomicAdd(&h[y[blockIdx.x * 256 + t]], 1);
  __syncthreads();
  if (t < DOUT) cnt[blockIdx.x * DOUT + t] = h[t];
}

__global__ __launch_bounds__(512) void scan_kernel(const int* __restrict__ cnt,
                                                   int* __restrict__ blockoff,
                                                   int* __restrict__ bnd_g) {
  __shared__ int buf[2][512 * DOUT];
  __shared__ int bnd[DOUT + 1];
  int t = threadIdx.x;
  int v[DOUT];
#pragma unroll
  for (int c = 0; c < DOUT; ++c) { v[c] = cnt[t * DOUT + c]; buf[0][t * DOUT + c] = v[c]; }
  __syncthreads();
  int src = 0;
  for (int off = 1; off < 512; off <<= 1) {
    int x[DOUT];
#pragma unroll
    for (int c = 0; c < DOUT; ++c) {
      x[c] = buf[src][t * DOUT + c];
      if (t >= off) x[c] += buf[src][(t - off) * DOUT + c];
    }
#pragma unroll
    for (int c = 0; c < DOUT; ++c) buf[1 - src][t * DOUT + c] = x[c];
    src ^= 1;
    __syncthreads();
  }
  if (t == 0) {
    bnd[0] = 0;
    for (int c = 0; c < DOUT; ++c) bnd[c + 1] = bnd[c] + buf[src][511 * DOUT + c];
    for (int k = 0; k <= DOUT; ++k) bnd_g[k] = bnd[k];
  }
  __syncthreads();
#pragma unroll
  for (int c = 0; c < DOUT; ++c)
    blockoff[t * DOUT + c] = bnd[c] + buf[src][t * DOUT + c] - v[c];  // exclusive
}

__global__ __launch_bounds__(256) void scatter_kernel(const int* __restrict__ y,
                                                      const int* __restrict__ blockoff,
                                                      int* __restrict__ invperm) {
  __shared__ int cur[DOUT];
  int t = threadIdx.x;
  if (t < DOUT) cur[t] = blockoff[blockIdx.x * DOUT + t];
  __syncthreads();
  int e = blockIdx.x * 256 + t;
  int p = atomicAdd(&cur[y[e]], 1);
  invperm[p] = e;   // sorted position -> original candidate index
}

// ---------------- encoder: rows @ W^T + b -> bf16 + L2E2-scaled sq norms ----------------
__global__ __launch_bounds__(256, 2) void encoder_kernel(
    const float* __restrict__ X, const float* __restrict__ W,
    const float* __restrict__ bias, const int* __restrict__ invperm,
    short* __restrict__ Zb, float* __restrict__ Sq) {
  __shared__ __align__(16) short As[DIMK * DIMK];
  __shared__ __align__(16) short Bs[DIMK * DIMK];
  __shared__ float bias_s[DIMK];
  __shared__ float sqacc[DIMK];
  int t = threadIdx.x;
  int rowbase = blockIdx.x * 128;
  if (t < DIMK) { bias_s[t] = bias[t]; sqacc[t] = 0.f; }
#pragma unroll
  for (int i = 0; i < 8; ++i) {
    int flat = i * 256 + t;
    int r = flat >> 4, sl = flat & 15;
    int g = sl ^ (r & 15);
    const float* srcW = W + r * DIMK + g * 8;
    float4 a0 = *(const float4*)srcW;
    float4 a1 = *(const float4*)(srcW + 4);
    s16x8 wv;
    wv[0] = f2bf(a0.x); wv[1] = f2bf(a0.y); wv[2] = f2bf(a0.z); wv[3] = f2bf(a0.w);
    wv[4] = f2bf(a1.x); wv[5] = f2bf(a1.y); wv[6] = f2bf(a1.z); wv[7] = f2bf(a1.w);
    *(s16x8*)(Bs + r * DIMK + sl * 8) = wv;
    int xr = rowbase + r;
    int gxr = invperm ? invperm[xr] : xr;
    const float* srcX = X + (size_t)gxr * DIMK + g * 8;
    float4 b0 = *(const float4*)srcX;
    float4 b1 = *(const float4*)(srcX + 4);
    s16x8 xv;
    xv[0] = f2bf(b0.x); xv[1] = f2bf(b0.y); xv[2] = f2bf(b0.z); xv[3] = f2bf(b0.w);
    xv[4] = f2bf(b1.x); xv[5] = f2bf(b1.y); xv[6] = f2bf(b1.z); xv[7] = f2bf(b1.w);
    *(s16x8*)(As + r * DIMK + sl * 8) = xv;
  }
  __syncthreads();
  int lane = t & 63, wid = t >> 6;
  int quad = lane >> 4, l15 = lane & 15;
  int wrow = (wid >> 1) * 64, wcol = (wid & 1) * 64;
  f32x4 acc[4][4];
  f32x4 z4 = {0.f, 0.f, 0.f, 0.f};
#pragma unroll
  for (int i = 0; i < 4; ++i)
#pragma unroll
    for (int j = 0; j < 4; ++j) acc[i][j] = z4;
  mfma_tile(As, Bs, acc, wrow, wcol, quad, l15);
#pragma unroll
  for (int ti = 0; ti < 4; ++ti) {
#pragma unroll
    for (int r = 0; r < 4; ++r) {
      int row_l = wrow + ti * 16 + quad * 4 + r;
      size_t grow = (size_t)(rowbase + row_l);
      float sqp = 0.f;
#pragma unroll
      for (int j = 0; j < 4; ++j) {
        int dcol = wcol + j * 16 + l15;
        float z = acc[ti][j][r] + bias_s[dcol];
        short hb = f2bf(z);
        float zr = bf2f(hb);           // sq computed from rounded value (consistency)
        sqp += zr * zr;
        Zb[grow * DIMK + dcol] = hb;
      }
      sqp += __shfl_xor(sqp, 1);
      sqp += __shfl_xor(sqp, 2);
      sqp += __shfl_xor(sqp, 4);
      sqp += __shfl_xor(sqp, 8);
      if (l15 == 0) atomicAdd(&sqacc[row_l], sqp);
    }
  }
  __syncthreads();
  if (t < DIMK) Sq[rowbase + t] = sqacc[t] * L2E2;   // pre-scaled for exp2 epilogue
}

// ---------------- main fused GEMM + dist + exp + class-accumulate ----------
// Grid (x = rowblock [16], y = chunk [128]). A-frags + row norms register-resident.
// B: 64-col sub-tiles double-buffered in exactly 32 KB LDS -> 5 blocks/CU target.
// Output: device-scope fp32 atomicAdd into accum[row][16] (class-binned).
__global__ __launch_bounds__(256, 5) void nca_main(
    const short* __restrict__ Zb, const short* __restrict__ Cb,
    const float* __restrict__ Sqz, const float* __restrict__ Sqc,
    const int* __restrict__ bnd_g, float* __restrict__ accum) {
  __shared__ __align__(16) short Bs[2][64 * DIMK];   // 2 x 16 KB == full LDS budget/5

  int t = threadIdx.x;
  int lane = t & 63, wid = t >> 6;
  int quad = lane >> 4, l15 = lane & 15;
  int wrow = wid * 32;                 // each wave owns a private 32-row strip
  int rowbase = blockIdx.x * 128;
  int colbase0 = blockIdx.y * COLS_PER_BLOCK;

  // chunk class range (<=2 classes per 1024-chunk: min class count ~13k >> 1024)
  int bnd[DOUT + 1];
#pragma unroll
  for (int k = 0; k <= DOUT; ++k) bnd[k] = bnd_g[k];
  int cls_lo = 0, cls_hi = 0;
#pragma unroll
  for (int k = 1; k < DOUT; ++k) {
    cls_lo += (colbase0 >= bnd[k]) ? 1 : 0;
    cls_hi += (colbase0 + COLS_PER_BLOCK - 1 >= bnd[k]) ? 1 : 0;
  }
  bool two = (cls_hi != cls_lo);
  int split = bnd[cls_hi];             // first col of hi class (only used if two)

  stage64(Cb + (size_t)colbase0 * DIMK, &Bs[0][0], t);

  // A fragments: A[m=l15][k=quad*8+j] per 16-row tile, direct from global.
  bf16x8 afrag[4][2];
#pragma unroll
  for (int ks = 0; ks < 4; ++ks)
#pragma unroll
    for (int ti = 0; ti < 2; ++ti)
      afrag[ks][ti] = *(const bf16x8*)(
          Zb + (size_t)(rowbase + wrow + ti * 16 + l15) * DIMK + ks * 32 + quad * 8);

  f32x2 szv2[2][2];                    // pre-scaled row norms, packed over r-pairs
#pragma unroll
  for (int ti = 0; ti < 2; ++ti) {
    f32x4 s4 = *(const f32x4*)(Sqz + rowbase + wrow + ti * 16 + quad * 4);
    szv2[ti][0] = (f32x2){s4[0], s4[1]};
    szv2[ti][1] = (f32x2){s4[2], s4[3]};
  }

  float sum[8], sumB[8];
#pragma unroll
  for (int i = 0; i < 8; ++i) { sum[i] = 0.f; sumB[i] = 0.f; }

  const f32x2 m2 = {-2.0f, -2.0f};

  for (int it = 0; it < SUB_ITERS; ++it) {
    int colb = colbase0 + it * 64;
    __syncthreads();     // drains stage of buf[it&1] (+ sqc loads); prev reads done

    // this-iter candidate norms: issue BEFORE next stage so waitcnt can leave
    // the staging loads in flight (they only need to land by the next barrier)
    float sqcv[4];
#pragma unroll
    for (int j = 0; j < 4; ++j) sqcv[j] = Sqc[colb + j * 16 + l15];

    if (it + 1 < SUB_ITERS)
      stage64(Cb + (size_t)(colb + 64) * DIMK, &Bs[(it + 1) & 1][0], t);
    const short* B = &Bs[it & 1][0];

    f32x4 acc[2][4];
    f32x4 z4 = {0.f, 0.f, 0.f, 0.f};
#pragma unroll
    for (int ti = 0; ti < 2; ++ti)
#pragma unroll
      for (int j = 0; j < 4; ++j) acc[ti][j] = z4;

#pragma unroll
    for (int ks = 0; ks < 4; ++ks) {
      int slot = (ks * 4 + quad) ^ l15;
      const short* p = B + l15 * DIMK + slot * 8;   // imm offsets encode j*16 rows
      bf16x8 b0 = *(const bf16x8*)(p);
      bf16x8 b1 = *(const bf16x8*)(p + 16 * DIMK);
      bf16x8 b2 = *(const bf16x8*)(p + 32 * DIMK);
      bf16x8 b3 = *(const bf16x8*)(p + 48 * DIMK);
#pragma unroll
      for (int ti = 0; ti < 2; ++ti) {
        acc[ti][0] = __builtin_amdgcn_mfma_f32_16x16x32_bf16(afrag[ks][ti], b0, acc[ti][0], 0, 0, 0);
        acc[ti][1] = __builtin_amdgcn_mfma_f32_16x16x32_bf16(afrag[ks][ti], b1, acc[ti][1], 0, 0, 0);
        acc[ti][2] = __builtin_amdgcn_mfma_f32_16x16x32_bf16(afrag[ks][ti], b2, acc[ti][2], 0, 0, 0);
        acc[ti][3] = __builtin_amdgcn_mfma_f32_16x16x32_bf16(afrag[ks][ti], b3, acc[ti][3], 0, 0, 0);
      }
    }

    if (!two) {
#pragma unroll
      for (int ti = 0; ti < 2; ++ti)
#pragma unroll
        for (int j = 0; j < 4; ++j) {
          f32x2 q = {sqcv[j], sqcv[j]};
          f32x2 s01 = szv2[ti][0] + q;            // v_pk_add_f32
          f32x2 s23 = szv2[ti][1] + q;
          f32x4 a = acc[ti][j];
          f32x2 a01 = {a[0], a[1]}, a23 = {a[2], a[3]};
          s01 = a01 * m2 + s01;                   // v_pk_fma_f32 (contract)
          s23 = a23 * m2 + s23;
          float e0 = fast_exp2f(-fast_sqrtf(__builtin_fabsf(s01[0])));
          float e1 = fast_exp2f(-fast_sqrtf(__builtin_fabsf(s01[1])));
          float e2 = fast_exp2f(-fast_sqrtf(__builtin_fabsf(s23[0])));
          float e3 = fast_exp2f(-fast_sqrtf(__builtin_fabsf(s23[1])));
          sum[ti * 4 + 0] += e0; sum[ti * 4 + 1] += e1;
          sum[ti * 4 + 2] += e2; sum[ti * 4 + 3] += e3;
        }
    } else {
      float mask[4];
#pragma unroll
      for (int j = 0; j < 4; ++j)
        mask[j] = (colb + j * 16 + l15 >= split) ? 1.0f : 0.0f;
#pragma unroll
      for (int ti = 0; ti < 2; ++ti)
#pragma unroll
        for (int j = 0; j < 4; ++j) {
          f32x2 q = {sqcv[j], sqcv[j]};
          f32x2 s01 = szv2[ti][0] + q;
          f32x2 s23 = szv2[ti][1] + q;
          f32x4 a = acc[ti][j];
          f32x2 a01 = {a[0], a[1]}, a23 = {a[2], a[3]};
          s01 = a01 * m2 + s01;
          s23 = a23 * m2 + s23;
          float e0 = fast_exp2f(-fast_sqrtf(__builtin_fabsf(s01[0])));
          float e1 = fast_exp2f(-fast_sqrtf(__builtin_fabsf(s01[1])));
          float e2 = fast_exp2f(-fast_sqrtf(__builtin_fabsf(s23[0])));
          float e3 = fast_exp2f(-fast_sqrtf(__builtin_fabsf(s23[1])));
          sum[ti * 4 + 0] += e0; sum[ti * 4 + 1] += e1;
          sum[ti * 4 + 2] += e2; sum[ti * 4 + 3] += e3;
          sumB[ti * 4 + 0] = fmaf(e0, mask[j], sumB[ti * 4 + 0]);  // v_fmac
          sumB[ti * 4 + 1] = fmaf(e1, mask[j], sumB[ti * 4 + 1]);
          sumB[ti * 4 + 2] = fmaf(e2, mask[j], sumB[ti * 4 + 2]);
          sumB[ti * 4 + 3] = fmaf(e3, mask[j], sumB[ti * 4 + 3]);
        }
    }
  }

  // per-row column-sum across the 16 l15 lanes, then class-binned atomic add
#pragma unroll
  for (int si = 0; si < 8; ++si) {
    float s = sum[si];
    s += __shfl_xor(s, 1);
    s += __shfl_xor(s, 2);
    s += __shfl_xor(s, 4);
    s += __shfl_xor(s, 8);
    float b = sumB[si];
    if (two) {
      b += __shfl_xor(b, 1);
      b += __shfl_xor(b, 2);
      b += __shfl_xor(b, 4);
      b += __shfl_xor(b, 8);
    }
    if (l15 == 0) {
      int row = rowbase + wrow + (si >> 2) * 16 + quad * 4 + (si & 3);
      if (!two) {
        atomicAdd(&accum[row * 16 + cls_lo], s);
      } else {
        atomicAdd(&accum[row * 16 + cls_lo], s - b);
        atomicAdd(&accum[row * 16 + cls_hi], b);
      }
    }
  }
}

// ---------------- final: normalize + log ----------------
__global__ __launch_bounds__(256) void logits_kernel(const float* __restrict__ accum,
                                                     float* __restrict__ out) {
  int i = blockIdx.x * 256 + threadIdx.x;
  if (i >= N_ROWS) return;
  float v[DOUT], tot = 0.f;
#pragma unroll
  for (int c = 0; c < DOUT; ++c) { v[c] = accum[i * 16 + c]; tot += v[c]; }
  float inv = 1.0f / tot;
#pragma unroll
  for (int c = 0; c < DOUT; ++c)
    out[(size_t)i * DOUT + c] = logf(fmaf(v[c], inv, 1e-7f));
}

extern "C" void kernel_launch(void* const* d_in, const int* in_sizes, int n_in,
                              void* d_out, int out_size, void* d_ws, size_t ws_size,
                              hipStream_t stream) {
  const float* x = (const float*)d_in[0];      // [2048][128]
  const float* cx = (const float*)d_in[1];     // [131072][128]
  const int* cy = (const int*)d_in[2];         // [131072]
  const float* W = (const float*)d_in[3];      // [128][128]
  const float* bias = (const float*)d_in[4];   // [128]
  float* out = (float*)d_out;
  char* ws = (char*)d_ws;

  size_t off = 0;
  auto alloc = [&](size_t bytes) {
    void* p = ws + off;
    off = (off + bytes + 255) & ~(size_t)255;
    return p;
  };
  short* Zb = (short*)alloc((size_t)N_ROWS * DIMK * 2);
  short* Cb = (short*)alloc((size_t)M_CAND * DIMK * 2);
  float* Sqz = (float*)alloc((size_t)N_ROWS * 4);
  float* Sqc = (float*)alloc((size_t)M_CAND * 4);
  int* invperm = (int*)alloc((size_t)M_CAND * 4);
  int* cnt = (int*)alloc(512 * DOUT * 4);
  int* blockoff = (int*)alloc(512 * DOUT * 4);
  int* bnd = (int*)alloc((DOUT + 1) * 4);
  float* accum = (float*)alloc((size_t)N_ROWS * 16 * 4);
  if (off > ws_size) return;   // ~36 MB needed

  hist_kernel<<<M_CAND / 256, 256, 0, stream>>>(cy, cnt, accum);
  scan_kernel<<<1, 512, 0, stream>>>(cnt, blockoff, bnd);
  scatter_kernel<<<M_CAND / 256, 256, 0, stream>>>(cy, blockoff, invperm);
  encoder_kernel<<<N_ROWS / 128, 256, 0, stream>>>(x, W, bias, nullptr, Zb, Sqz);
  encoder_kernel<<<M_CAND / 128, 256, 0, stream>>>(cx, W, bias, invperm, Cb, Sqc);
  nca_main<<<dim3(N_ROWS / 128, CHUNKS), 256, 0, stream>>>(Zb, Cb, Sqz, Sqc, bnd, accum);
  logits_kernel<<<(N_ROWS + 255) / 256, 256, 0, stream>>>(accum, out);
}

// Round 5
// 339.676 us; speedup vs baseline: 1.2386x; 1.2386x over previous
//
#include <hip/hip_runtime.h>
#include <stdint.h>
#include <math.h>

#define N_ROWS 2048
#define M_CAND 131072
#define DIMK 128
#define DOUT 10
#define COLS_PER_BLOCK 1024       // one chunk per block; M = 128 * 1024 exactly
#define SUB_ITERS 16              // 16 sub-tiles of 64 candidates
#define CHUNKS (M_CAND / COLS_PER_BLOCK)   // 128
#define LOG2E 1.4426950408889634f
#define L2E2 (LOG2E * LOG2E)      // pre-scale so exp2(-sqrt(sq')) == exp(-sqrt(sq))

typedef __attribute__((ext_vector_type(8))) __bf16 bf16x8;   // MFMA A/B frag (4 VGPRs)
typedef __attribute__((ext_vector_type(8))) short s16x8;     // raw bf16 storage vec
typedef __attribute__((ext_vector_type(4))) float f32x4;     // MFMA C/D frag
typedef __attribute__((ext_vector_type(2))) float f32x2;     // v_pk_* pair
typedef __attribute__((address_space(3))) void lds_void;
typedef const __attribute__((address_space(1))) void gbl_void;

__device__ __forceinline__ short f2bf(float f) {   // RNE fp32->bf16
  union { float f; unsigned u; } v; v.f = f;
  return (short)((v.u + 0x7fffu + ((v.u >> 16) & 1u)) >> 16);
}
__device__ __forceinline__ float bf2f(short h) {
  union { unsigned u; float f; } v;
  v.u = ((unsigned)(unsigned short)h) << 16; return v.f;
}
__device__ __forceinline__ float fast_sqrtf(float x) {
#if __has_builtin(__builtin_amdgcn_sqrtf)
  return __builtin_amdgcn_sqrtf(x);
#else
  return sqrtf(x);
#endif
}
__device__ __forceinline__ float fast_exp2f(float x) {
#if __has_builtin(__builtin_amdgcn_exp2f)
  return __builtin_amdgcn_exp2f(x);
#else
  return exp2f(x);
#endif
}

// Swizzled 64x128 bf16 tile: LDS slot (r,s) [16B granules] holds global granule g = s^(r&15).
__device__ __forceinline__ void stage64(const short* gbase, short* lds, int t) {
  int w = t >> 6;
#pragma unroll
  for (int i = 0; i < 4; ++i) {
    int flat = i * 256 + t;
    int r = flat >> 4, s = flat & 15;
    int g = s ^ (r & 15);
    const short* src = gbase + r * DIMK + g * 8;
    short* dst = lds + (i * 256 + w * 64) * 8;   // wave-uniform base; HW adds lane*16B
    __builtin_amdgcn_global_load_lds((gbl_void*)src, (lds_void*)dst, 16, 0, 0);
  }
}

// 64x64 wave tile, K=128 (encoder; both operands in swizzled 128x128 LDS tiles)
__device__ __forceinline__ void mfma_tile(const short* As, const short* Bs,
                                          f32x4 acc[4][4], int wrow, int wcol,
                                          int quad, int l15) {
#pragma unroll
  for (int ks = 0; ks < 4; ++ks) {
    int slot = (ks * 4 + quad) ^ l15;
    bf16x8 a[4], b[4];
#pragma unroll
    for (int i = 0; i < 4; ++i) {
      a[i] = *(const bf16x8*)(As + (wrow + i * 16 + l15) * DIMK + slot * 8);
      b[i] = *(const bf16x8*)(Bs + (wcol + i * 16 + l15) * DIMK + slot * 8);
    }
#pragma unroll
    for (int i = 0; i < 4; ++i)
#pragma unroll
      for (int j = 0; j < 4; ++j)
        acc[i][j] = __builtin_amdgcn_mfma_f32_16x16x32_bf16(a[i], b[j], acc[i][j], 0, 0, 0);
  }
}

// ---------------- preprocessing: class-sort candidates (exact, no padding) ------------
// hist also zeroes the accum[2048][16] output accumulator (first 128 blocks).
__global__ __launch_bounds__(256) void hist_kernel(const int* __restrict__ y,
                                                   int* __restrict__ cnt,
                                                   float* __restrict__ accum) {
  __shared__ int h[DOUT];
  int t = threadIdx.x;
  if (blockIdx.x < 128) accum[blockIdx.x * 256 + t] = 0.f;   // 2048*16 floats
  if (t < DOUT) h[t] = 0;
  __syncthreads();
  atomicAdd(&h[y[blockIdx.x * 256 + t]], 1);
  __syncthreads();
  if (t < DOUT) cnt[blockIdx.x * DOUT + t] = h[t];
}

__global__ __launch_bounds__(512) void scan_kernel(const int* __restrict__ cnt,
                                                   int* __restrict__ blockoff,
                                                   int* __restrict__ bnd_g) {
  __shared__ int buf[2][512 * DOUT];
  __shared__ int bnd[DOUT + 1];
  int t = threadIdx.x;
  int v[DOUT];
#pragma unroll
  for (int c = 0; c < DOUT; ++c) { v[c] = cnt[t * DOUT + c]; buf[0][t * DOUT + c] = v[c]; }
  __syncthreads();
  int src = 0;
  for (int off = 1; off < 512; off <<= 1) {
    int x[DOUT];
#pragma unroll
    for (int c = 0; c < DOUT; ++c) {
      x[c] = buf[src][t * DOUT + c];
      if (t >= off) x[c] += buf[src][(t - off) * DOUT + c];
    }
#pragma unroll
    for (int c = 0; c < DOUT; ++c) buf[1 - src][t * DOUT + c] = x[c];
    src ^= 1;
    __syncthreads();
  }
  if (t == 0) {
    bnd[0] = 0;
    for (int c = 0; c < DOUT; ++c) bnd[c + 1] = bnd[c] + buf[src][511 * DOUT + c];
    for (int k = 0; k <= DOUT; ++k) bnd_g[k] = bnd[k];
  }
  __syncthreads();
#pragma unroll
  for (int c = 0; c < DOUT; ++c)
    blockoff[t * DOUT + c] = bnd[c] + buf[src][t * DOUT + c] - v[c];  // exclusive
}

__global__ __launch_bounds__(256) void scatter_kernel(const int* __restrict__ y,
                                                      const int* __restrict__ blockoff,
                                                      int* __restrict__ invperm) {
  __shared__ int cur[DOUT];
  int t = threadIdx.x;
  if (t < DOUT) cur[t] = blockoff[blockIdx.x * DOUT + t];
  __syncthreads();
  int e = blockIdx.x * 256 + t;
  int p = atomicAdd(&cur[y[e]], 1);
  invperm[p] = e;   // sorted position -> original candidate index
}

// ---------------- encoder: rows @ W^T + b -> bf16 + L2E2-scaled sq norms ----------------
__global__ __launch_bounds__(256, 2) void encoder_kernel(
    const float* __restrict__ X, const float* __restrict__ W,
    const float* __restrict__ bias, const int* __restrict__ invperm,
    short* __restrict__ Zb, float* __restrict__ Sq) {
  __shared__ __align__(16) short As[DIMK * DIMK];
  __shared__ __align__(16) short Bs[DIMK * DIMK];
  __shared__ float bias_s[DIMK];
  __shared__ float sqacc[DIMK];
  int t = threadIdx.x;
  int rowbase = blockIdx.x * 128;
  if (t < DIMK) { bias_s[t] = bias[t]; sqacc[t] = 0.f; }
#pragma unroll
  for (int i = 0; i < 8; ++i) {
    int flat = i * 256 + t;
    int r = flat >> 4, sl = flat & 15;
    int g = sl ^ (r & 15);
    const float* srcW = W + r * DIMK + g * 8;
    float4 a0 = *(const float4*)srcW;
    float4 a1 = *(const float4*)(srcW + 4);
    s16x8 wv;
    wv[0] = f2bf(a0.x); wv[1] = f2bf(a0.y); wv[2] = f2bf(a0.z); wv[3] = f2bf(a0.w);
    wv[4] = f2bf(a1.x); wv[5] = f2bf(a1.y); wv[6] = f2bf(a1.z); wv[7] = f2bf(a1.w);
    *(s16x8*)(Bs + r * DIMK + sl * 8) = wv;
    int xr = rowbase + r;
    int gxr = invperm ? invperm[xr] : xr;
    const float* srcX = X + (size_t)gxr * DIMK + g * 8;
    float4 b0 = *(const float4*)srcX;
    float4 b1 = *(const float4*)(srcX + 4);
    s16x8 xv;
    xv[0] = f2bf(b0.x); xv[1] = f2bf(b0.y); xv[2] = f2bf(b0.z); xv[3] = f2bf(b0.w);
    xv[4] = f2bf(b1.x); xv[5] = f2bf(b1.y); xv[6] = f2bf(b1.z); xv[7] = f2bf(b1.w);
    *(s16x8*)(As + r * DIMK + sl * 8) = xv;
  }
  __syncthreads();
  int lane = t & 63, wid = t >> 6;
  int quad = lane >> 4, l15 = lane & 15;
  int wrow = (wid >> 1) * 64, wcol = (wid & 1) * 64;
  f32x4 acc[4][4];
  f32x4 z4 = {0.f, 0.f, 0.f, 0.f};
#pragma unroll
  for (int i = 0; i < 4; ++i)
#pragma unroll
    for (int j = 0; j < 4; ++j) acc[i][j] = z4;
  mfma_tile(As, Bs, acc, wrow, wcol, quad, l15);
#pragma unroll
  for (int ti = 0; ti < 4; ++ti) {
#pragma unroll
    for (int r = 0; r < 4; ++r) {
      int row_l = wrow + ti * 16 + quad * 4 + r;
      size_t grow = (size_t)(rowbase + row_l);
      float sqp = 0.f;
#pragma unroll
      for (int j = 0; j < 4; ++j) {
        int dcol = wcol + j * 16 + l15;
        float z = acc[ti][j][r] + bias_s[dcol];
        short hb = f2bf(z);
        float zr = bf2f(hb);           // sq computed from rounded value (consistency)
        sqp += zr * zr;
        Zb[grow * DIMK + dcol] = hb;
      }
      sqp += __shfl_xor(sqp, 1);
      sqp += __shfl_xor(sqp, 2);
      sqp += __shfl_xor(sqp, 4);
      sqp += __shfl_xor(sqp, 8);
      if (l15 == 0) atomicAdd(&sqacc[row_l], sqp);
    }
  }
  __syncthreads();
  if (t < DIMK) Sq[rowbase + t] = sqacc[t] * L2E2;   // pre-scaled for exp2 epilogue
}

// ---------------- main fused GEMM + dist + exp + class-accumulate ----------
// Grid (x = rowblock [16], y = chunk [128]). A-frags + row norms register-resident.
// B: 64-col sub-tiles double-buffered in exactly 32 KB LDS.
// launch_bounds(256,4): VGPR cap 128 -> NO SPILL (R4's (256,5) spilled: 1.16 GB
// scratch HBM traffic). LDS 32 KB still admits 5 blocks/CU if VGPRs <= 96.
__global__ __launch_bounds__(256, 4) void nca_main(
    const short* __restrict__ Zb, const short* __restrict__ Cb,
    const float* __restrict__ Sqz, const float* __restrict__ Sqc,
    const int* __restrict__ bnd_g, float* __restrict__ accum) {
  __shared__ __align__(16) short Bs[2][64 * DIMK];   // 2 x 16 KB

  int t = threadIdx.x;
  int lane = t & 63, wid = t >> 6;
  int quad = lane >> 4, l15 = lane & 15;
  int wrow = wid * 32;                 // each wave owns a private 32-row strip
  int rowbase = blockIdx.x * 128;
  int colbase0 = blockIdx.y * COLS_PER_BLOCK;

  // chunk class range (<=2 classes per 1024-chunk: min class count ~13k >> 1024)
  int bnd[DOUT + 1];
#pragma unroll
  for (int k = 0; k <= DOUT; ++k) bnd[k] = bnd_g[k];
  int cls_lo = 0, cls_hi = 0;
#pragma unroll
  for (int k = 1; k < DOUT; ++k) {
    cls_lo += (colbase0 >= bnd[k]) ? 1 : 0;
    cls_hi += (colbase0 + COLS_PER_BLOCK - 1 >= bnd[k]) ? 1 : 0;
  }
  bool two = (cls_hi != cls_lo);
  int split = bnd[cls_hi];             // first col of hi class (only used if two)

  stage64(Cb + (size_t)colbase0 * DIMK, &Bs[0][0], t);

  // A fragments: A[m=l15][k=quad*8+j] per 16-row tile, direct from global.
  bf16x8 afrag[4][2];
#pragma unroll
  for (int ks = 0; ks < 4; ++ks)
#pragma unroll
    for (int ti = 0; ti < 2; ++ti)
      afrag[ks][ti] = *(const bf16x8*)(
          Zb + (size_t)(rowbase + wrow + ti * 16 + l15) * DIMK + ks * 32 + quad * 8);

  f32x2 szv2[2][2];                    // pre-scaled row norms, packed over r-pairs
#pragma unroll
  for (int ti = 0; ti < 2; ++ti) {
    f32x4 s4 = *(const f32x4*)(Sqz + rowbase + wrow + ti * 16 + quad * 4);
    szv2[ti][0] = (f32x2){s4[0], s4[1]};
    szv2[ti][1] = (f32x2){s4[2], s4[3]};
  }

  float sum[8], sumB[8];
#pragma unroll
  for (int i = 0; i < 8; ++i) { sum[i] = 0.f; sumB[i] = 0.f; }

  // norms are pre-scaled by L2E2; cross term must carry the SAME scale:
  // sq' = L2E2*sz + L2E2*sc + (-2*L2E2)*acc   (R4 bug: used -2 here)
  const f32x2 m2 = {-2.0f * L2E2, -2.0f * L2E2};

  for (int it = 0; it < SUB_ITERS; ++it) {
    int colb = colbase0 + it * 64;
    __syncthreads();     // drains stage of buf[it&1]; prev-iter reads complete

    float sqcv[4];
#pragma unroll
    for (int j = 0; j < 4; ++j) sqcv[j] = Sqc[colb + j * 16 + l15];

    if (it + 1 < SUB_ITERS)
      stage64(Cb + (size_t)(colb + 64) * DIMK, &Bs[(it + 1) & 1][0], t);
    const short* B = &Bs[it & 1][0];

    f32x4 acc[2][4];
    f32x4 z4 = {0.f, 0.f, 0.f, 0.f};
#pragma unroll
    for (int ti = 0; ti < 2; ++ti)
#pragma unroll
      for (int j = 0; j < 4; ++j) acc[ti][j] = z4;

#pragma unroll
    for (int ks = 0; ks < 4; ++ks) {
      int slot = (ks * 4 + quad) ^ l15;
      const short* p = B + l15 * DIMK + slot * 8;   // imm offsets encode j*16 rows
      bf16x8 b0 = *(const bf16x8*)(p);
      bf16x8 b1 = *(const bf16x8*)(p + 16 * DIMK);
      bf16x8 b2 = *(const bf16x8*)(p + 32 * DIMK);
      bf16x8 b3 = *(const bf16x8*)(p + 48 * DIMK);
#pragma unroll
      for (int ti = 0; ti < 2; ++ti) {
        acc[ti][0] = __builtin_amdgcn_mfma_f32_16x16x32_bf16(afrag[ks][ti], b0, acc[ti][0], 0, 0, 0);
        acc[ti][1] = __builtin_amdgcn_mfma_f32_16x16x32_bf16(afrag[ks][ti], b1, acc[ti][1], 0, 0, 0);
        acc[ti][2] = __builtin_amdgcn_mfma_f32_16x16x32_bf16(afrag[ks][ti], b2, acc[ti][2], 0, 0, 0);
        acc[ti][3] = __builtin_amdgcn_mfma_f32_16x16x32_bf16(afrag[ks][ti], b3, acc[ti][3], 0, 0, 0);
      }
    }

    if (!two) {
#pragma unroll
      for (int ti = 0; ti < 2; ++ti)
#pragma unroll
        for (int j = 0; j < 4; ++j) {
          f32x2 q = {sqcv[j], sqcv[j]};
          f32x2 s01 = szv2[ti][0] + q;            // v_pk_add_f32
          f32x2 s23 = szv2[ti][1] + q;
          f32x4 a = acc[ti][j];
          f32x2 a01 = {a[0], a[1]}, a23 = {a[2], a[3]};
          s01 = a01 * m2 + s01;                   // v_pk_fma_f32 (contract)
          s23 = a23 * m2 + s23;
          float e0 = fast_exp2f(-fast_sqrtf(__builtin_fabsf(s01[0])));
          float e1 = fast_exp2f(-fast_sqrtf(__builtin_fabsf(s01[1])));
          float e2 = fast_exp2f(-fast_sqrtf(__builtin_fabsf(s23[0])));
          float e3 = fast_exp2f(-fast_sqrtf(__builtin_fabsf(s23[1])));
          sum[ti * 4 + 0] += e0; sum[ti * 4 + 1] += e1;
          sum[ti * 4 + 2] += e2; sum[ti * 4 + 3] += e3;
        }
    } else {
      float mask[4];
#pragma unroll
      for (int j = 0; j < 4; ++j)
        mask[j] = (colb + j * 16 + l15 >= split) ? 1.0f : 0.0f;
#pragma unroll
      for (int ti = 0; ti < 2; ++ti)
#pragma unroll
        for (int j = 0; j < 4; ++j) {
          f32x2 q = {sqcv[j], sqcv[j]};
          f32x2 s01 = szv2[ti][0] + q;
          f32x2 s23 = szv2[ti][1] + q;
          f32x4 a = acc[ti][j];
          f32x2 a01 = {a[0], a[1]}, a23 = {a[2], a[3]};
          s01 = a01 * m2 + s01;
          s23 = a23 * m2 + s23;
          float e0 = fast_exp2f(-fast_sqrtf(__builtin_fabsf(s01[0])));
          float e1 = fast_exp2f(-fast_sqrtf(__builtin_fabsf(s01[1])));
          float e2 = fast_exp2f(-fast_sqrtf(__builtin_fabsf(s23[0])));
          float e3 = fast_exp2f(-fast_sqrtf(__builtin_fabsf(s23[1])));
          sum[ti * 4 + 0] += e0; sum[ti * 4 + 1] += e1;
          sum[ti * 4 + 2] += e2; sum[ti * 4 + 3] += e3;
          sumB[ti * 4 + 0] = fmaf(e0, mask[j], sumB[ti * 4 + 0]);
          sumB[ti * 4 + 1] = fmaf(e1, mask[j], sumB[ti * 4 + 1]);
          sumB[ti * 4 + 2] = fmaf(e2, mask[j], sumB[ti * 4 + 2]);
          sumB[ti * 4 + 3] = fmaf(e3, mask[j], sumB[ti * 4 + 3]);
        }
    }
  }

  // per-row column-sum across the 16 l15 lanes, then class-binned atomic add
#pragma unroll
  for (int si = 0; si < 8; ++si) {
    float s = sum[si];
    s += __shfl_xor(s, 1);
    s += __shfl_xor(s, 2);
    s += __shfl_xor(s, 4);
    s += __shfl_xor(s, 8);
    float b = sumB[si];
    if (two) {
      b += __shfl_xor(b, 1);
      b += __shfl_xor(b, 2);
      b += __shfl_xor(b, 4);
      b += __shfl_xor(b, 8);
    }
    if (l15 == 0) {
      int row = rowbase + wrow + (si >> 2) * 16 + quad * 4 + (si & 3);
      if (!two) {
        atomicAdd(&accum[row * 16 + cls_lo], s);
      } else {
        atomicAdd(&accum[row * 16 + cls_lo], s - b);
        atomicAdd(&accum[row * 16 + cls_hi], b);
      }
    }
  }
}

// ---------------- final: normalize + log ----------------
__global__ __launch_bounds__(256) void logits_kernel(const float* __restrict__ accum,
                                                     float* __restrict__ out) {
  int i = blockIdx.x * 256 + threadIdx.x;
  if (i >= N_ROWS) return;
  float v[DOUT], tot = 0.f;
#pragma unroll
  for (int c = 0; c < DOUT; ++c) { v[c] = accum[i * 16 + c]; tot += v[c]; }
  float inv = 1.0f / tot;
#pragma unroll
  for (int c = 0; c < DOUT; ++c)
    out[(size_t)i * DOUT + c] = logf(fmaf(v[c], inv, 1e-7f));
}

extern "C" void kernel_launch(void* const* d_in, const int* in_sizes, int n_in,
                              void* d_out, int out_size, void* d_ws, size_t ws_size,
                              hipStream_t stream) {
  const float* x = (const float*)d_in[0];      // [2048][128]
  const float* cx = (const float*)d_in[1];     // [131072][128]
  const int* cy = (const int*)d_in[2];         // [131072]
  const float* W = (const float*)d_in[3];      // [128][128]
  const float* bias = (const float*)d_in[4];   // [128]
  float* out = (float*)d_out;
  char* ws = (char*)d_ws;

  size_t off = 0;
  auto alloc = [&](size_t bytes) {
    void* p = ws + off;
    off = (off + bytes + 255) & ~(size_t)255;
    return p;
  };
  short* Zb = (short*)alloc((size_t)N_ROWS * DIMK * 2);
  short* Cb = (short*)alloc((size_t)M_CAND * DIMK * 2);
  float* Sqz = (float*)alloc((size_t)N_ROWS * 4);
  float* Sqc = (float*)alloc((size_t)M_CAND * 4);
  int* invperm = (int*)alloc((size_t)M_CAND * 4);
  int* cnt = (int*)alloc(512 * DOUT * 4);
  int* blockoff = (int*)alloc(512 * DOUT * 4);
  int* bnd = (int*)alloc((DOUT + 1) * 4);
  float* accum = (float*)alloc((size_t)N_ROWS * 16 * 4);
  if (off > ws_size) return;   // ~36 MB needed

  hist_kernel<<<M_CAND / 256, 256, 0, stream>>>(cy, cnt, accum);
  scan_kernel<<<1, 512, 0, stream>>>(cnt, blockoff, bnd);
  scatter_kernel<<<M_CAND / 256, 256, 0, stream>>>(cy, blockoff, invperm);
  encoder_kernel<<<N_ROWS / 128, 256, 0, stream>>>(x, W, bias, nullptr, Zb, Sqz);
  encoder_kernel<<<M_CAND / 128, 256, 0, stream>>>(cx, W, bias, invperm, Cb, Sqc);
  nca_main<<<dim3(N_ROWS / 128, CHUNKS), 256, 0, stream>>>(Zb, Cb, Sqz, Sqc, bnd, accum);
  logits_kernel<<<(N_ROWS + 255) / 256, 256, 0, stream>>>(accum, out);
}

// Round 6
// 263.006 us; speedup vs baseline: 1.5996x; 1.2915x over previous
//
#include <hip/hip_runtime.h>
#include <stdint.h>
#include <math.h>

#define N_ROWS 2048
#define M_CAND 131072
#define DIMK 128
#define DOUT 10
#define COLS_PER_BLOCK 1024       // one chunk per block (class-uniform, padded)
#define SUB_ITERS 16              // 16 sub-tiles of 64 candidates
#define CHUNKS_MAX 138            // ceil(M/1024) + DOUT (class-padding worst case)
#define M_PAD_MAX (CHUNKS_MAX * COLS_PER_BLOCK)   // 141312
#define LOG2E 1.4426950408889634f
#define L2E2 (LOG2E * LOG2E)      // norms pre-scaled: exp2(-sqrt(sq')) == exp(-sqrt(sq))

typedef __attribute__((ext_vector_type(8))) __bf16 bf16x8;   // MFMA A/B frag (4 VGPRs)
typedef __attribute__((ext_vector_type(8))) short s16x8;     // raw bf16 storage vec
typedef __attribute__((ext_vector_type(4))) float f32x4;     // MFMA C/D frag
typedef __attribute__((ext_vector_type(2))) float f32x2;     // v_pk_* pair
typedef __attribute__((address_space(3))) void lds_void;
typedef const __attribute__((address_space(1))) void gbl_void;

__device__ __forceinline__ short f2bf(float f) {   // RNE fp32->bf16
  union { float f; unsigned u; } v; v.f = f;
  return (short)((v.u + 0x7fffu + ((v.u >> 16) & 1u)) >> 16);
}
__device__ __forceinline__ float bf2f(short h) {
  union { unsigned u; float f; } v;
  v.u = ((unsigned)(unsigned short)h) << 16; return v.f;
}
__device__ __forceinline__ float fast_sqrtf(float x) {
#if __has_builtin(__builtin_amdgcn_sqrtf)
  return __builtin_amdgcn_sqrtf(x);
#else
  return sqrtf(x);
#endif
}
__device__ __forceinline__ float fast_exp2f(float x) {
#if __has_builtin(__builtin_amdgcn_exp2f)
  return __builtin_amdgcn_exp2f(x);
#else
  return exp2f(x);
#endif
}

// Swizzled 64x128 bf16 tile: LDS slot (r,s) [16B granules] holds global granule g = s^(r&15).
__device__ __forceinline__ void stage64(const short* gbase, short* lds, int t) {
  int w = t >> 6;
#pragma unroll
  for (int i = 0; i < 4; ++i) {
    int flat = i * 256 + t;
    int r = flat >> 4, s = flat & 15;
    int g = s ^ (r & 15);
    const short* src = gbase + r * DIMK + g * 8;
    short* dst = lds + (i * 256 + w * 64) * 8;   // wave-uniform base; HW adds lane*16B
    __builtin_amdgcn_global_load_lds((gbl_void*)src, (lds_void*)dst, 16, 0, 0);
  }
}

// 64x64 wave tile, K=128 (encoder; both operands in swizzled 128x128 LDS tiles)
__device__ __forceinline__ void mfma_tile(const short* As, const short* Bs,
                                          f32x4 acc[4][4], int wrow, int wcol,
                                          int quad, int l15) {
#pragma unroll
  for (int ks = 0; ks < 4; ++ks) {
    int slot = (ks * 4 + quad) ^ l15;
    bf16x8 a[4], b[4];
#pragma unroll
    for (int i = 0; i < 4; ++i) {
      a[i] = *(const bf16x8*)(As + (wrow + i * 16 + l15) * DIMK + slot * 8);
      b[i] = *(const bf16x8*)(Bs + (wcol + i * 16 + l15) * DIMK + slot * 8);
    }
#pragma unroll
    for (int i = 0; i < 4; ++i)
#pragma unroll
      for (int j = 0; j < 4; ++j)
        acc[i][j] = __builtin_amdgcn_mfma_f32_16x16x32_bf16(a[i], b[j], acc[i][j], 0, 0, 0);
  }
}

// ---------------- preprocessing: class-sort candidates (padded to 1024/class) ------------
__global__ __launch_bounds__(256) void hist_kernel(const int* __restrict__ y,
                                                   int* __restrict__ cnt) {
  __shared__ int h[DOUT];
  int t = threadIdx.x;
  if (t < DOUT) h[t] = 0;
  __syncthreads();
  atomicAdd(&h[y[blockIdx.x * 256 + t]], 1);
  __syncthreads();
  if (t < DOUT) cnt[blockIdx.x * DOUT + t] = h[t];
}

// scan + padded boundaries + chunk classes + pad invperm entries (fill fused here)
__global__ __launch_bounds__(512) void scan_kernel(const int* __restrict__ cnt,
                                                   int* __restrict__ blockoff,
                                                   int* __restrict__ chunk_class,
                                                   int* __restrict__ invperm) {
  __shared__ int buf[2][512 * DOUT];
  __shared__ int pbnd[DOUT + 1];
  __shared__ int ccnt[DOUT];
  int t = threadIdx.x;
  int v[DOUT];
#pragma unroll
  for (int c = 0; c < DOUT; ++c) { v[c] = cnt[t * DOUT + c]; buf[0][t * DOUT + c] = v[c]; }
  __syncthreads();
  int src = 0;
  for (int off = 1; off < 512; off <<= 1) {
    int x[DOUT];
#pragma unroll
    for (int c = 0; c < DOUT; ++c) {
      x[c] = buf[src][t * DOUT + c];
      if (t >= off) x[c] += buf[src][(t - off) * DOUT + c];
    }
#pragma unroll
    for (int c = 0; c < DOUT; ++c) buf[1 - src][t * DOUT + c] = x[c];
    src ^= 1;
    __syncthreads();
  }
  if (t == 0) {
    int pb = 0;
    pbnd[0] = 0;
    for (int c = 0; c < DOUT; ++c) {
      int tot = buf[src][511 * DOUT + c];
      ccnt[c] = tot;
      pb += (tot + COLS_PER_BLOCK - 1) & ~(COLS_PER_BLOCK - 1);  // pad class to 1024
      pbnd[c + 1] = pb;
    }
  }
  __syncthreads();
  if (t < CHUNKS_MAX) {
    int col = t * COLS_PER_BLOCK, c = 0;
#pragma unroll
    for (int k = 1; k < DOUT; ++k) c += (col >= pbnd[k]) ? 1 : 0;
    chunk_class[t] = c;             // dead chunks -> class 9; they contribute exactly 0
  }
  // pad entries of invperm: [pbnd[c]+ccnt[c], pbnd[c+1]) = -1  (<= 10K total)
  for (int c = 0; c < DOUT; ++c)
    for (int i = pbnd[c] + ccnt[c] + t; i < pbnd[c + 1]; i += 512) invperm[i] = -1;
  // tail pads beyond last class up to M_PAD_MAX
  for (int i = pbnd[DOUT] + t; i < M_PAD_MAX; i += 512) invperm[i] = -1;
#pragma unroll
  for (int c = 0; c < DOUT; ++c)
    blockoff[t * DOUT + c] = pbnd[c] + buf[src][t * DOUT + c] - v[c];  // padded exclusive
}

__global__ __launch_bounds__(256) void scatter_kernel(const int* __restrict__ y,
                                                      const int* __restrict__ blockoff,
                                                      int* __restrict__ invperm) {
  __shared__ int cur[DOUT];
  int t = threadIdx.x;
  if (t < DOUT) cur[t] = blockoff[blockIdx.x * DOUT + t];
  __syncthreads();
  int e = blockIdx.x * 256 + t;
  int p = atomicAdd(&cur[y[e]], 1);
  invperm[p] = e;   // padded sorted position -> original candidate index
}

// ---------------- encoder: rows @ W^T + b -> bf16 + L2E2-scaled sq norms ----------------
__global__ __launch_bounds__(256, 2) void encoder_kernel(
    const float* __restrict__ X, const float* __restrict__ W,
    const float* __restrict__ bias, const int* __restrict__ invperm,
    short* __restrict__ Zb, float* __restrict__ Sq) {
  __shared__ __align__(16) short As[DIMK * DIMK];
  __shared__ __align__(16) short Bs[DIMK * DIMK];
  __shared__ float bias_s[DIMK];
  __shared__ float sqacc[DIMK];
  int t = threadIdx.x;
  int rowbase = blockIdx.x * 128;
  if (t < DIMK) { bias_s[t] = bias[t]; sqacc[t] = 0.f; }
#pragma unroll
  for (int i = 0; i < 8; ++i) {
    int flat = i * 256 + t;
    int r = flat >> 4, sl = flat & 15;
    int g = sl ^ (r & 15);
    const float* srcW = W + r * DIMK + g * 8;
    float4 a0 = *(const float4*)srcW;
    float4 a1 = *(const float4*)(srcW + 4);
    s16x8 wv;
    wv[0] = f2bf(a0.x); wv[1] = f2bf(a0.y); wv[2] = f2bf(a0.z); wv[3] = f2bf(a0.w);
    wv[4] = f2bf(a1.x); wv[5] = f2bf(a1.y); wv[6] = f2bf(a1.z); wv[7] = f2bf(a1.w);
    *(s16x8*)(Bs + r * DIMK + sl * 8) = wv;
    int xr = rowbase + r;
    int gxr = invperm ? invperm[xr] : xr;
    const float* srcX = X + (size_t)(gxr < 0 ? 0 : gxr) * DIMK + g * 8;
    float4 b0 = *(const float4*)srcX;
    float4 b1 = *(const float4*)(srcX + 4);
    if (gxr < 0) { b0 = make_float4(0.f, 0.f, 0.f, 0.f); b1 = b0; }
    s16x8 xv;
    xv[0] = f2bf(b0.x); xv[1] = f2bf(b0.y); xv[2] = f2bf(b0.z); xv[3] = f2bf(b0.w);
    xv[4] = f2bf(b1.x); xv[5] = f2bf(b1.y); xv[6] = f2bf(b1.z); xv[7] = f2bf(b1.w);
    *(s16x8*)(As + r * DIMK + sl * 8) = xv;
  }
  __syncthreads();
  int lane = t & 63, wid = t >> 6;
  int quad = lane >> 4, l15 = lane & 15;
  int wrow = (wid >> 1) * 64, wcol = (wid & 1) * 64;
  f32x4 acc[4][4];
  f32x4 z4 = {0.f, 0.f, 0.f, 0.f};
#pragma unroll
  for (int i = 0; i < 4; ++i)
#pragma unroll
    for (int j = 0; j < 4; ++j) acc[i][j] = z4;
  mfma_tile(As, Bs, acc, wrow, wcol, quad, l15);
#pragma unroll
  for (int ti = 0; ti < 4; ++ti) {
#pragma unroll
    for (int r = 0; r < 4; ++r) {
      int row_l = wrow + ti * 16 + quad * 4 + r;
      size_t grow = (size_t)(rowbase + row_l);
      float sqp = 0.f;
#pragma unroll
      for (int j = 0; j < 4; ++j) {
        int dcol = wcol + j * 16 + l15;
        float z = acc[ti][j][r] + bias_s[dcol];
        short hb = f2bf(z);
        float zr = bf2f(hb);           // sq computed from rounded value (consistency)
        sqp += zr * zr;
        Zb[grow * DIMK + dcol] = hb;
      }
      sqp += __shfl_xor(sqp, 1);
      sqp += __shfl_xor(sqp, 2);
      sqp += __shfl_xor(sqp, 4);
      sqp += __shfl_xor(sqp, 8);
      if (l15 == 0) atomicAdd(&sqacc[row_l], sqp);
    }
  }
  __syncthreads();
  if (t < DIMK) {
    bool dead = invperm && (invperm[rowbase + t] < 0);
    Sq[rowbase + t] = dead ? 1e30f : sqacc[t] * L2E2;  // pre-scaled; pads -> exp == 0
  }
}

// ---------------- main fused GEMM + dist + exp + per-block sum ----------
// R3-proven structure: padded single-class chunks -> NO class logic in the hot
// loop, sum[8] only (R4/R5's sumB/mask/bnd pushed regalloc into in-loop scratch
// spill: 488 MB phantom WRITE_SIZE). A-frags register-resident; B 64-col
// sub-tiles double-buffered in LDS; sqc staged once; partials store (no atomics).
__global__ __launch_bounds__(256, 4) void nca_main(
    const short* __restrict__ Zb, const short* __restrict__ Cb,
    const float* __restrict__ Sqz, const float* __restrict__ Sqc,
    float* __restrict__ partials) {
  __shared__ __align__(16) short Bs[2][64 * DIMK];   // 2 x 16 KB
  __shared__ float sqc_s[COLS_PER_BLOCK];            // 4 KB (pre-scaled norms)

  int t = threadIdx.x;
  int lane = t & 63, wid = t >> 6;
  int quad = lane >> 4, l15 = lane & 15;
  int wrow = wid * 32;                 // each wave owns a private 32-row strip
  int rowbase = blockIdx.x * 128;
  int colbase0 = blockIdx.y * COLS_PER_BLOCK;

  stage64(Cb + (size_t)colbase0 * DIMK, &Bs[0][0], t);

#pragma unroll
  for (int i = 0; i < 4; ++i)
    sqc_s[i * 256 + t] = Sqc[colbase0 + i * 256 + t];

  // A fragments: A[m=l15][k=quad*8+j] per 16-row tile, direct from global.
  bf16x8 afrag[4][2];
#pragma unroll
  for (int ks = 0; ks < 4; ++ks)
#pragma unroll
    for (int ti = 0; ti < 2; ++ti)
      afrag[ks][ti] = *(const bf16x8*)(
          Zb + (size_t)(rowbase + wrow + ti * 16 + l15) * DIMK + ks * 32 + quad * 8);

  f32x2 szv2[2][2];                    // pre-scaled row norms, packed over r-pairs
#pragma unroll
  for (int ti = 0; ti < 2; ++ti) {
    f32x4 s4 = *(const f32x4*)(Sqz + rowbase + wrow + ti * 16 + quad * 4);
    szv2[ti][0] = (f32x2){s4[0], s4[1]};
    szv2[ti][1] = (f32x2){s4[2], s4[3]};
  }

  float sum[8];
#pragma unroll
  for (int i = 0; i < 8; ++i) sum[i] = 0.f;

  // norms carry L2E2; cross term must carry the same scale
  const f32x2 m2 = {-2.0f * L2E2, -2.0f * L2E2};

  for (int it = 0; it < SUB_ITERS; ++it) {
    __syncthreads();     // drains stage of buf[it&1]; prev-iter reads complete
    if (it + 1 < SUB_ITERS)
      stage64(Cb + (size_t)(colbase0 + (it + 1) * 64) * DIMK, &Bs[(it + 1) & 1][0], t);
    const short* B = &Bs[it & 1][0];

    f32x4 acc[2][4];
    f32x4 z4 = {0.f, 0.f, 0.f, 0.f};
#pragma unroll
    for (int ti = 0; ti < 2; ++ti)
#pragma unroll
      for (int j = 0; j < 4; ++j) acc[ti][j] = z4;

#pragma unroll
    for (int ks = 0; ks < 4; ++ks) {
      int slot = (ks * 4 + quad) ^ l15;
      const short* p = B + l15 * DIMK + slot * 8;   // imm offsets encode j*16 rows
      bf16x8 b0 = *(const bf16x8*)(p);
      bf16x8 b1 = *(const bf16x8*)(p + 16 * DIMK);
      bf16x8 b2 = *(const bf16x8*)(p + 32 * DIMK);
      bf16x8 b3 = *(const bf16x8*)(p + 48 * DIMK);
#pragma unroll
      for (int ti = 0; ti < 2; ++ti) {
        acc[ti][0] = __builtin_amdgcn_mfma_f32_16x16x32_bf16(afrag[ks][ti], b0, acc[ti][0], 0, 0, 0);
        acc[ti][1] = __builtin_amdgcn_mfma_f32_16x16x32_bf16(afrag[ks][ti], b1, acc[ti][1], 0, 0, 0);
        acc[ti][2] = __builtin_amdgcn_mfma_f32_16x16x32_bf16(afrag[ks][ti], b2, acc[ti][2], 0, 0, 0);
        acc[ti][3] = __builtin_amdgcn_mfma_f32_16x16x32_bf16(afrag[ks][ti], b3, acc[ti][3], 0, 0, 0);
      }
    }

    float sqcv[4];
#pragma unroll
    for (int j = 0; j < 4; ++j) sqcv[j] = sqc_s[it * 64 + j * 16 + l15];
#pragma unroll
    for (int ti = 0; ti < 2; ++ti)
#pragma unroll
      for (int j = 0; j < 4; ++j) {
        f32x2 q = {sqcv[j], sqcv[j]};
        f32x2 s01 = szv2[ti][0] + q;            // v_pk_add_f32
        f32x2 s23 = szv2[ti][1] + q;
        f32x4 a = acc[ti][j];
        f32x2 a01 = {a[0], a[1]}, a23 = {a[2], a[3]};
        s01 = a01 * m2 + s01;                   // v_pk_fma_f32
        s23 = a23 * m2 + s23;
        float e0 = fast_exp2f(-fast_sqrtf(__builtin_fabsf(s01[0])));
        float e1 = fast_exp2f(-fast_sqrtf(__builtin_fabsf(s01[1])));
        float e2 = fast_exp2f(-fast_sqrtf(__builtin_fabsf(s23[0])));
        float e3 = fast_exp2f(-fast_sqrtf(__builtin_fabsf(s23[1])));
        sum[ti * 4 + 0] += e0; sum[ti * 4 + 1] += e1;
        sum[ti * 4 + 2] += e2; sum[ti * 4 + 3] += e3;
      }
  }

  // per-row column-sum: reduce across the 16 l15 lanes, once per block
#pragma unroll
  for (int si = 0; si < 8; ++si) {
    float s = sum[si];
    s += __shfl_xor(s, 1);
    s += __shfl_xor(s, 2);
    s += __shfl_xor(s, 4);
    s += __shfl_xor(s, 8);
    if (l15 == 0) {
      int row_l = wrow + (si >> 2) * 16 + quad * 4 + (si & 3);
      partials[(size_t)blockIdx.y * N_ROWS + rowbase + row_l] = s;
    }
  }
}

// ---------------- final reduce over chunks, class binning + log ----------------
__global__ __launch_bounds__(64) void reduce_kernel(const float* __restrict__ partials,
                                                    const int* __restrict__ chunk_class,
                                                    float* __restrict__ out) {
  int row = blockIdx.x, lane = threadIdx.x;
  float s = 0.f;
  for (int ch = 0; ch < CHUNKS_MAX; ++ch) {
    float p = partials[(size_t)ch * N_ROWS + row];
    int c = chunk_class[ch];
    s += (lane == c) ? p : 0.f;
  }
  float tot = s;
  tot += __shfl_xor(tot, 1);
  tot += __shfl_xor(tot, 2);
  tot += __shfl_xor(tot, 4);
  tot += __shfl_xor(tot, 8);
  tot += __shfl_xor(tot, 16);
  tot += __shfl_xor(tot, 32);
  if (lane < DOUT)
    out[(size_t)row * DOUT + lane] = logf(s / tot + 1e-7f);
}

extern "C" void kernel_launch(void* const* d_in, const int* in_sizes, int n_in,
                              void* d_out, int out_size, void* d_ws, size_t ws_size,
                              hipStream_t stream) {
  const float* x = (const float*)d_in[0];      // [2048][128]
  const float* cx = (const float*)d_in[1];     // [131072][128]
  const int* cy = (const int*)d_in[2];         // [131072]
  const float* W = (const float*)d_in[3];      // [128][128]
  const float* bias = (const float*)d_in[4];   // [128]
  float* out = (float*)d_out;
  char* ws = (char*)d_ws;

  size_t off = 0;
  auto alloc = [&](size_t bytes) {
    void* p = ws + off;
    off = (off + bytes + 255) & ~(size_t)255;
    return p;
  };
  short* Zb = (short*)alloc((size_t)N_ROWS * DIMK * 2);
  short* Cb = (short*)alloc((size_t)M_PAD_MAX * DIMK * 2);
  float* Sqz = (float*)alloc((size_t)N_ROWS * 4);
  float* Sqc = (float*)alloc((size_t)M_PAD_MAX * 4);
  int* invperm = (int*)alloc((size_t)M_PAD_MAX * 4);
  int* cnt = (int*)alloc(512 * DOUT * 4);
  int* blockoff = (int*)alloc(512 * DOUT * 4);
  int* chunk_class = (int*)alloc(CHUNKS_MAX * 4);
  float* partials = (float*)alloc((size_t)CHUNKS_MAX * N_ROWS * 4);
  if (off > ws_size) return;   // ~40 MB needed

  hist_kernel<<<M_CAND / 256, 256, 0, stream>>>(cy, cnt);
  scan_kernel<<<1, 512, 0, stream>>>(cnt, blockoff, chunk_class, invperm);
  scatter_kernel<<<M_CAND / 256, 256, 0, stream>>>(cy, blockoff, invperm);
  encoder_kernel<<<N_ROWS / 128, 256, 0, stream>>>(x, W, bias, nullptr, Zb, Sqz);
  encoder_kernel<<<M_PAD_MAX / 128, 256, 0, stream>>>(cx, W, bias, invperm, Cb, Sqc);
  nca_main<<<dim3(N_ROWS / 128, CHUNKS_MAX), 256, 0, stream>>>(Zb, Cb, Sqz, Sqc, partials);
  reduce_kernel<<<N_ROWS, 64, 0, stream>>>(partials, chunk_class, out);
}

// Round 7
// 246.070 us; speedup vs baseline: 1.7097x; 1.0688x over previous
//
#include <hip/hip_runtime.h>
#include <stdint.h>
#include <math.h>

#define N_ROWS 2048
#define M_CAND 131072
#define DIMK 128
#define DOUT 10
#define COLS_PER_BLOCK 1024       // one chunk per block (class-uniform, padded)
#define SUB_ITERS 16              // 16 sub-tiles of 64 candidates
#define CHUNKS_MAX 138            // ceil(M/1024) + DOUT (class-padding worst case)
#define M_PAD_MAX (CHUNKS_MAX * COLS_PER_BLOCK)   // 141312
#define LOG2E 1.4426950408889634f
#define L2E2 (LOG2E * LOG2E)      // norms pre-scaled: exp2(-sqrt(sq')) == exp(-sqrt(sq))

typedef __attribute__((ext_vector_type(8))) __bf16 bf16x8;   // MFMA A/B frag (4 VGPRs)
typedef __attribute__((ext_vector_type(8))) short s16x8;     // raw bf16 storage vec
typedef __attribute__((ext_vector_type(4))) float f32x4;     // MFMA C/D frag
typedef __attribute__((ext_vector_type(2))) float f32x2;     // v_pk_* pair
typedef __attribute__((address_space(3))) void lds_void;
typedef const __attribute__((address_space(1))) void gbl_void;

union frag_cast { s16x8 s; bf16x8 b; };

__device__ __forceinline__ short f2bf(float f) {   // RNE fp32->bf16
  union { float f; unsigned u; } v; v.f = f;
  return (short)((v.u + 0x7fffu + ((v.u >> 16) & 1u)) >> 16);
}
__device__ __forceinline__ float bf2f(short h) {
  union { unsigned u; float f; } v;
  v.u = ((unsigned)(unsigned short)h) << 16; return v.f;
}
__device__ __forceinline__ float fast_sqrtf(float x) {
#if __has_builtin(__builtin_amdgcn_sqrtf)
  return __builtin_amdgcn_sqrtf(x);
#else
  return sqrtf(x);
#endif
}
__device__ __forceinline__ float fast_exp2f(float x) {
#if __has_builtin(__builtin_amdgcn_exp2f)
  return __builtin_amdgcn_exp2f(x);
#else
  return exp2f(x);
#endif
}

// Swizzled 64x128 bf16 tile: LDS slot (r,s) [16B granules] holds global granule g = s^(r&15).
__device__ __forceinline__ void stage64(const short* gbase, short* lds, int t) {
  int w = t >> 6;
#pragma unroll
  for (int i = 0; i < 4; ++i) {
    int flat = i * 256 + t;
    int r = flat >> 4, s = flat & 15;
    int g = s ^ (r & 15);
    const short* src = gbase + r * DIMK + g * 8;
    short* dst = lds + (i * 256 + w * 64) * 8;   // wave-uniform base; HW adds lane*16B
    __builtin_amdgcn_global_load_lds((gbl_void*)src, (lds_void*)dst, 16, 0, 0);
  }
}

// Swizzled 128x128 bf16 tile stage (encoder: W)
__device__ __forceinline__ void stage128(const short* gbase, short* lds, int t) {
  int w = t >> 6;
#pragma unroll
  for (int i = 0; i < 8; ++i) {
    int flat = i * 256 + t;
    int r = flat >> 4, s = flat & 15;
    int g = s ^ (r & 15);
    const short* src = gbase + r * DIMK + g * 8;
    short* dst = lds + (i * 256 + w * 64) * 8;
    __builtin_amdgcn_global_load_lds((gbl_void*)src, (lds_void*)dst, 16, 0, 0);
  }
}

// ---------------- preprocessing: class-sort candidates (padded to 1024/class) ------------
__global__ __launch_bounds__(256) void hist_kernel(const int* __restrict__ y,
                                                   int* __restrict__ cnt) {
  __shared__ int h[DOUT];
  int t = threadIdx.x;
  if (t < DOUT) h[t] = 0;
  __syncthreads();
  atomicAdd(&h[y[blockIdx.x * 256 + t]], 1);
  __syncthreads();
  if (t < DOUT) cnt[blockIdx.x * DOUT + t] = h[t];
}

// scan + padded boundaries + chunk classes + pad invperm entries
__global__ __launch_bounds__(512) void scan_kernel(const int* __restrict__ cnt,
                                                   int* __restrict__ blockoff,
                                                   int* __restrict__ chunk_class,
                                                   int* __restrict__ invperm) {
  __shared__ int buf[2][512 * DOUT];
  __shared__ int pbnd[DOUT + 1];
  __shared__ int ccnt[DOUT];
  int t = threadIdx.x;
  int v[DOUT];
#pragma unroll
  for (int c = 0; c < DOUT; ++c) { v[c] = cnt[t * DOUT + c]; buf[0][t * DOUT + c] = v[c]; }
  __syncthreads();
  int src = 0;
  for (int off = 1; off < 512; off <<= 1) {
    int x[DOUT];
#pragma unroll
    for (int c = 0; c < DOUT; ++c) {
      x[c] = buf[src][t * DOUT + c];
      if (t >= off) x[c] += buf[src][(t - off) * DOUT + c];
    }
#pragma unroll
    for (int c = 0; c < DOUT; ++c) buf[1 - src][t * DOUT + c] = x[c];
    src ^= 1;
    __syncthreads();
  }
  if (t == 0) {
    int pb = 0;
    pbnd[0] = 0;
    for (int c = 0; c < DOUT; ++c) {
      int tot = buf[src][511 * DOUT + c];
      ccnt[c] = tot;
      pb += (tot + COLS_PER_BLOCK - 1) & ~(COLS_PER_BLOCK - 1);  // pad class to 1024
      pbnd[c + 1] = pb;
    }
  }
  __syncthreads();
  if (t < CHUNKS_MAX) {
    int col = t * COLS_PER_BLOCK, c = 0;
#pragma unroll
    for (int k = 1; k < DOUT; ++k) c += (col >= pbnd[k]) ? 1 : 0;
    chunk_class[t] = c;             // dead chunks -> class 9; they contribute exactly 0
  }
  // pad entries of invperm: [pbnd[c]+ccnt[c], pbnd[c+1]) = -1
  for (int c = 0; c < DOUT; ++c)
    for (int i = pbnd[c] + ccnt[c] + t; i < pbnd[c + 1]; i += 512) invperm[i] = -1;
  for (int i = pbnd[DOUT] + t; i < M_PAD_MAX; i += 512) invperm[i] = -1;
#pragma unroll
  for (int c = 0; c < DOUT; ++c)
    blockoff[t * DOUT + c] = pbnd[c] + buf[src][t * DOUT + c] - v[c];  // padded exclusive
}

__global__ __launch_bounds__(256) void scatter_kernel(const int* __restrict__ y,
                                                      const int* __restrict__ blockoff,
                                                      int* __restrict__ invperm) {
  __shared__ int cur[DOUT];
  int t = threadIdx.x;
  if (t < DOUT) cur[t] = blockoff[blockIdx.x * DOUT + t];
  __syncthreads();
  int e = blockIdx.x * 256 + t;
  int p = atomicAdd(&cur[y[e]], 1);
  invperm[p] = e;   // padded sorted position -> original candidate index
}

// ---------------- W fp32 -> bf16 (once) ----------------
__global__ __launch_bounds__(256) void convert_w_kernel(const float* __restrict__ W,
                                                        short* __restrict__ Wb) {
  int i = blockIdx.x * 256 + threadIdx.x;   // 16384 elems
  Wb[i] = f2bf(W[i]);
}

// ---------------- encoder v2: rows @ W^T + b -> bf16 + L2E2-scaled sq norms ----------
// Only W (bf16, 32 KB) goes through LDS; A-fragments converted fp32->bf16 in
// registers straight from global. 64 rows/block (4 waves x 16 rows x 128 cols).
__global__ __launch_bounds__(256, 4) void encoder2_kernel(
    const float* __restrict__ X, const short* __restrict__ Wb,
    const float* __restrict__ bias, const int* __restrict__ invperm,
    short* __restrict__ Zb, float* __restrict__ Sq) {
  __shared__ __align__(16) short Ws[DIMK * DIMK];   // 32 KB swizzled W tile
  int t = threadIdx.x;
  int lane = t & 63, wid = t >> 6;
  int quad = lane >> 4, l15 = lane & 15;
  int rowbase = blockIdx.x * 64 + wid * 16;

  stage128(Wb, Ws, t);

  int grow = rowbase + l15;                 // this lane's A-row
  int gxr = invperm ? invperm[grow] : grow;
  bool dead = (gxr < 0);

  bf16x8 afrag[4];
#pragma unroll
  for (int ks = 0; ks < 4; ++ks) {
    frag_cast fc;
    if (!dead) {
      const float* p = X + (size_t)gxr * DIMK + ks * 32 + quad * 8;
      float4 x0 = *(const float4*)p;
      float4 x1 = *(const float4*)(p + 4);
      fc.s[0] = f2bf(x0.x); fc.s[1] = f2bf(x0.y); fc.s[2] = f2bf(x0.z); fc.s[3] = f2bf(x0.w);
      fc.s[4] = f2bf(x1.x); fc.s[5] = f2bf(x1.y); fc.s[6] = f2bf(x1.z); fc.s[7] = f2bf(x1.w);
    } else {
      fc.s = (s16x8){0, 0, 0, 0, 0, 0, 0, 0};
    }
    afrag[ks] = fc.b;
  }

  float bias_v[8];
#pragma unroll
  for (int j = 0; j < 8; ++j) bias_v[j] = bias[j * 16 + l15];

  __syncthreads();                          // W staged (vmcnt drained here)

  f32x4 acc[8];
#pragma unroll
  for (int j = 0; j < 8; ++j) acc[j] = (f32x4){0.f, 0.f, 0.f, 0.f};

#pragma unroll
  for (int ks = 0; ks < 4; ++ks) {
    int slot = (ks * 4 + quad) ^ l15;
    const short* p = Ws + l15 * DIMK + slot * 8;   // imm offsets encode j*16 rows
#pragma unroll
    for (int j = 0; j < 8; ++j) {
      bf16x8 b = *(const bf16x8*)(p + j * 16 * DIMK);
      acc[j] = __builtin_amdgcn_mfma_f32_16x16x32_bf16(afrag[ks], b, acc[j], 0, 0, 0);
    }
  }

  float sqp[4] = {0.f, 0.f, 0.f, 0.f};
#pragma unroll
  for (int j = 0; j < 8; ++j) {
#pragma unroll
    for (int r = 0; r < 4; ++r) {
      float z = acc[j][r] + bias_v[j];
      short hb = f2bf(z);
      float zr = bf2f(hb);                  // sq from rounded value (consistency)
      sqp[r] = fmaf(zr, zr, sqp[r]);
      Zb[(size_t)(rowbase + quad * 4 + r) * DIMK + j * 16 + l15] = hb;
    }
  }
#pragma unroll
  for (int r = 0; r < 4; ++r) {
    float s = sqp[r];
    s += __shfl_xor(s, 1);
    s += __shfl_xor(s, 2);
    s += __shfl_xor(s, 4);
    s += __shfl_xor(s, 8);
    if (l15 == 0) {
      int row = rowbase + quad * 4 + r;
      bool drow = invperm && (invperm[row] < 0);
      Sq[row] = drow ? 1e30f : s * L2E2;    // pre-scaled; pad rows -> exp == 0
    }
  }
}

// ---------------- main fused GEMM + dist + exp + per-block sum ----------
// Padded single-class chunks -> no class logic in hot loop. A-frags register-
// resident; B 64-col sub-tiles double-buffered in EXACTLY 32 KB LDS -> 5
// blocks/CU (R6 was 36.9 KB -> 4). Sqc read per-iter from global (L2-hot).
__global__ __launch_bounds__(256, 4) void nca_main(
    const short* __restrict__ Zb, const short* __restrict__ Cb,
    const float* __restrict__ Sqz, const float* __restrict__ Sqc,
    float* __restrict__ partials) {
  __shared__ __align__(16) short Bs[2][64 * DIMK];   // 2 x 16 KB == 32 KB total

  int t = threadIdx.x;
  int lane = t & 63, wid = t >> 6;
  int quad = lane >> 4, l15 = lane & 15;
  int wrow = wid * 32;                 // each wave owns a private 32-row strip
  int rowbase = blockIdx.x * 128;
  int colbase0 = blockIdx.y * COLS_PER_BLOCK;

  stage64(Cb + (size_t)colbase0 * DIMK, &Bs[0][0], t);

  // A fragments: A[m=l15][k=quad*8+j] per 16-row tile, direct from global.
  bf16x8 afrag[4][2];
#pragma unroll
  for (int ks = 0; ks < 4; ++ks)
#pragma unroll
    for (int ti = 0; ti < 2; ++ti)
      afrag[ks][ti] = *(const bf16x8*)(
          Zb + (size_t)(rowbase + wrow + ti * 16 + l15) * DIMK + ks * 32 + quad * 8);

  f32x2 szv2[2][2];                    // pre-scaled row norms, packed over r-pairs
#pragma unroll
  for (int ti = 0; ti < 2; ++ti) {
    f32x4 s4 = *(const f32x4*)(Sqz + rowbase + wrow + ti * 16 + quad * 4);
    szv2[ti][0] = (f32x2){s4[0], s4[1]};
    szv2[ti][1] = (f32x2){s4[2], s4[3]};
  }

  f32x2 sum2[4];                       // packed accumulators (r-pairs)
#pragma unroll
  for (int i = 0; i < 4; ++i) sum2[i] = (f32x2){0.f, 0.f};

  // norms carry L2E2; cross term must carry the same scale
  const f32x2 m2 = {-2.0f * L2E2, -2.0f * L2E2};

  for (int it = 0; it < SUB_ITERS; ++it) {
    int colb = colbase0 + it * 64;
    __syncthreads();     // drains stage of buf[it&1]; prev-iter reads complete

    // candidate norms straight from global (L2-hot); issued early to hide latency
    float sqcv[4];
#pragma unroll
    for (int j = 0; j < 4; ++j) sqcv[j] = Sqc[colb + j * 16 + l15];

    if (it + 1 < SUB_ITERS)
      stage64(Cb + (size_t)(colb + 64) * DIMK, &Bs[(it + 1) & 1][0], t);
    const short* B = &Bs[it & 1][0];

    f32x4 acc[2][4];
    f32x4 z4 = {0.f, 0.f, 0.f, 0.f};
#pragma unroll
    for (int ti = 0; ti < 2; ++ti)
#pragma unroll
      for (int j = 0; j < 4; ++j) acc[ti][j] = z4;

#pragma unroll
    for (int ks = 0; ks < 4; ++ks) {
      int slot = (ks * 4 + quad) ^ l15;
      const short* p = B + l15 * DIMK + slot * 8;   // imm offsets encode j*16 rows
      bf16x8 b0 = *(const bf16x8*)(p);
      bf16x8 b1 = *(const bf16x8*)(p + 16 * DIMK);
      bf16x8 b2 = *(const bf16x8*)(p + 32 * DIMK);
      bf16x8 b3 = *(const bf16x8*)(p + 48 * DIMK);
#pragma unroll
      for (int ti = 0; ti < 2; ++ti) {
        acc[ti][0] = __builtin_amdgcn_mfma_f32_16x16x32_bf16(afrag[ks][ti], b0, acc[ti][0], 0, 0, 0);
        acc[ti][1] = __builtin_amdgcn_mfma_f32_16x16x32_bf16(afrag[ks][ti], b1, acc[ti][1], 0, 0, 0);
        acc[ti][2] = __builtin_amdgcn_mfma_f32_16x16x32_bf16(afrag[ks][ti], b2, acc[ti][2], 0, 0, 0);
        acc[ti][3] = __builtin_amdgcn_mfma_f32_16x16x32_bf16(afrag[ks][ti], b3, acc[ti][3], 0, 0, 0);
      }
    }

#pragma unroll
    for (int ti = 0; ti < 2; ++ti)
#pragma unroll
      for (int j = 0; j < 4; ++j) {
        f32x2 q = {sqcv[j], sqcv[j]};
        f32x2 s01 = szv2[ti][0] + q;            // v_pk_add_f32
        f32x2 s23 = szv2[ti][1] + q;
        f32x4 a = acc[ti][j];
        f32x2 a01 = {a[0], a[1]}, a23 = {a[2], a[3]};
        s01 = a01 * m2 + s01;                   // v_pk_fma_f32
        s23 = a23 * m2 + s23;
        float e0 = fast_exp2f(-fast_sqrtf(__builtin_fabsf(s01[0])));
        float e1 = fast_exp2f(-fast_sqrtf(__builtin_fabsf(s01[1])));
        float e2 = fast_exp2f(-fast_sqrtf(__builtin_fabsf(s23[0])));
        float e3 = fast_exp2f(-fast_sqrtf(__builtin_fabsf(s23[1])));
        sum2[ti * 2 + 0] += (f32x2){e0, e1};    // v_pk_add_f32 accumulate
        sum2[ti * 2 + 1] += (f32x2){e2, e3};
      }
  }

  // per-row column-sum: reduce across the 16 l15 lanes, once per block
#pragma unroll
  for (int si = 0; si < 8; ++si) {
    float s = sum2[si >> 1][si & 1];
    s += __shfl_xor(s, 1);
    s += __shfl_xor(s, 2);
    s += __shfl_xor(s, 4);
    s += __shfl_xor(s, 8);
    if (l15 == 0) {
      int row_l = wrow + (si >> 2) * 16 + quad * 4 + (si & 3);
      partials[(size_t)blockIdx.y * N_ROWS + rowbase + row_l] = s;
    }
  }
}

// ---------------- final reduce over chunks, class binning + log ----------------
__global__ __launch_bounds__(64) void reduce_kernel(const float* __restrict__ partials,
                                                    const int* __restrict__ chunk_class,
                                                    float* __restrict__ out) {
  int row = blockIdx.x, lane = threadIdx.x;
  float s = 0.f;
  for (int ch = 0; ch < CHUNKS_MAX; ++ch) {
    float p = partials[(size_t)ch * N_ROWS + row];
    int c = chunk_class[ch];
    s += (lane == c) ? p : 0.f;
  }
  float tot = s;
  tot += __shfl_xor(tot, 1);
  tot += __shfl_xor(tot, 2);
  tot += __shfl_xor(tot, 4);
  tot += __shfl_xor(tot, 8);
  tot += __shfl_xor(tot, 16);
  tot += __shfl_xor(tot, 32);
  if (lane < DOUT)
    out[(size_t)row * DOUT + lane] = logf(s / tot + 1e-7f);
}

extern "C" void kernel_launch(void* const* d_in, const int* in_sizes, int n_in,
                              void* d_out, int out_size, void* d_ws, size_t ws_size,
                              hipStream_t stream) {
  const float* x = (const float*)d_in[0];      // [2048][128]
  const float* cx = (const float*)d_in[1];     // [131072][128]
  const int* cy = (const int*)d_in[2];         // [131072]
  const float* W = (const float*)d_in[3];      // [128][128]
  const float* bias = (const float*)d_in[4];   // [128]
  float* out = (float*)d_out;
  char* ws = (char*)d_ws;

  size_t off = 0;
  auto alloc = [&](size_t bytes) {
    void* p = ws + off;
    off = (off + bytes + 255) & ~(size_t)255;
    return p;
  };
  short* Zb = (short*)alloc((size_t)N_ROWS * DIMK * 2);
  short* Cb = (short*)alloc((size_t)M_PAD_MAX * DIMK * 2);
  short* Wb = (short*)alloc((size_t)DIMK * DIMK * 2);
  float* Sqz = (float*)alloc((size_t)N_ROWS * 4);
  float* Sqc = (float*)alloc((size_t)M_PAD_MAX * 4);
  int* invperm = (int*)alloc((size_t)M_PAD_MAX * 4);
  int* cnt = (int*)alloc(512 * DOUT * 4);
  int* blockoff = (int*)alloc(512 * DOUT * 4);
  int* chunk_class = (int*)alloc(CHUNKS_MAX * 4);
  float* partials = (float*)alloc((size_t)CHUNKS_MAX * N_ROWS * 4);
  if (off > ws_size) return;   // ~40 MB needed

  hist_kernel<<<M_CAND / 256, 256, 0, stream>>>(cy, cnt);
  scan_kernel<<<1, 512, 0, stream>>>(cnt, blockoff, chunk_class, invperm);
  scatter_kernel<<<M_CAND / 256, 256, 0, stream>>>(cy, blockoff, invperm);
  convert_w_kernel<<<DIMK * DIMK / 256, 256, 0, stream>>>(W, Wb);
  encoder2_kernel<<<N_ROWS / 64, 256, 0, stream>>>(x, Wb, bias, nullptr, Zb, Sqz);
  encoder2_kernel<<<M_PAD_MAX / 64, 256, 0, stream>>>(cx, Wb, bias, invperm, Cb, Sqc);
  nca_main<<<dim3(N_ROWS / 128, CHUNKS_MAX), 256, 0, stream>>>(Zb, Cb, Sqz, Sqc, partials);
  reduce_kernel<<<N_ROWS, 64, 0, stream>>>(partials, chunk_class, out);
}